// Round 8
// baseline (5834.937 us; speedup 1.0000x reference)
//
#include <hip/hip_runtime.h>
#include <hip/hip_bf16.h>
#include <hip/hip_fp16.h>
#include <cstddef>

// Problem constants: B=64, T=512, D=1024, H=1024
#define BATCH 64
#define TT    512
#define DD    1024
#define HH    1024

typedef _Float16 f16x8 __attribute__((ext_vector_type(8)));
typedef _Float16 f16x4 __attribute__((ext_vector_type(4)));
typedef float    f32x4 __attribute__((ext_vector_type(4)));
typedef unsigned long long u64;

union H8U2 { f16x8 v; u64 u[2]; };
union H4U1 { f16x4 h; u64 u; };

#define MFMA16(a, b, c) __builtin_amdgcn_mfma_f32_16x16x32_f16((a), (b), (c), 0, 0, 0)

// ---- convert: W [1024][1024] f32 row-major -> A-fragment-order f16 --------
// Wf[((cg*32+kk)*64+lane)*8+e] = W[k][c]  with  k = kk*32+(lane>>4)*8+e,
// c = cg*16+(lane&15).  (Layout verified rounds 1-6.)
// Optionally zeroes the h double-buffer (tag reset; 128 blks x 256 thr x 8B).
__global__ __launch_bounds__(256) void convert_w(
    const float* __restrict__ W, _Float16* __restrict__ Wf,
    u64* __restrict__ hzero)
{
    if (hzero && blockIdx.x < 128)
        hzero[(size_t)blockIdx.x * 256 + threadIdx.x] = 0ull;

    int tid = blockIdx.x * 256 + threadIdx.x;   // tid = k*1024 + c
    int k   = tid >> 10;
    int c   = tid & 1023;
    float v = W[tid];
    int cg   = c >> 4;
    int kk   = k >> 5;
    int lane = ((k >> 3) & 3) * 16 + (c & 15);
    int e    = k & 7;
    Wf[((size_t)(cg * 32 + kk) * 64 + lane) * 8 + e] = (_Float16)v;
}

// ---- Kernel A: xp = x @ Wx + bias via f16 MFMA (unchanged, works) ---------
__global__ __launch_bounds__(256, 1) void gemm_xp_mfma(
    const float* __restrict__ x,     // [32768][1024] f32
    const _Float16* __restrict__ WxA,// frag-ordered Wx^T
    const float* __restrict__ bias,  // [1024]
    float* __restrict__ out)         // [32768][1024] -> xp
{
    const int w    = threadIdx.x >> 6;
    const int lane = threadIdx.x & 63;
    const int l15  = lane & 15;
    const int lq   = lane >> 4;
    const int token0 = (blockIdx.x * 4 + w) * 16;

    f16x8 bfrag[32];
    {
        const float* xb = x + (size_t)(token0 + l15) * DD + lq * 8;
#pragma unroll
        for (int kk = 0; kk < 32; ++kk) {
            f32x4 lo = *(const f32x4*)(xb + kk * 32);
            f32x4 hi = *(const f32x4*)(xb + kk * 32 + 4);
            f16x8 f;
#pragma unroll
            for (int j = 0; j < 4; ++j) { f[j] = (_Float16)lo[j]; f[4 + j] = (_Float16)hi[j]; }
            bfrag[kk] = f;
        }
    }
#pragma unroll
    for (int kk = 0; kk < 32; ++kk) asm volatile("" : "+v"(bfrag[kk]));

    const size_t outb = (size_t)(token0 + l15) * HH + 4 * lq;

    for (int cg = 0; cg < 64; ++cg) {
        const f16x8* ap = (const f16x8*)WxA + (size_t)cg * 32 * 64 + lane;
        f16x8 a[32];
#pragma unroll
        for (int kk = 0; kk < 32; ++kk) a[kk] = ap[(size_t)kk * 64];

        f32x4 acc0 = {0,0,0,0}, acc1 = {0,0,0,0}, acc2 = {0,0,0,0}, acc3 = {0,0,0,0};
#pragma unroll
        for (int q = 0; q < 8; ++q) {
            acc0 = MFMA16(a[q*4+0], bfrag[q*4+0], acc0);
            acc1 = MFMA16(a[q*4+1], bfrag[q*4+1], acc1);
            acc2 = MFMA16(a[q*4+2], bfrag[q*4+2], acc2);
            acc3 = MFMA16(a[q*4+3], bfrag[q*4+3], acc3);
        }
        f32x4 bv = *(const f32x4*)(bias + cg * 16 + 4 * lq);
        f32x4 r;
#pragma unroll
        for (int v = 0; v < 4; ++v)
            r[v] = ((acc0[v] + acc1[v]) + (acc2[v] + acc3[v])) + bv[v];
        *(f32x4*)(out + outb + cg * 16) = r;
    }
}

// ---- Kernel B: persistent scan, 64 waves, 4 phase-staggered batch tiles ---
// Wave cg (= blockIdx.x, one wave per block) owns channels [16cg,16cg+16)
// for ALL 64 batches, processed as 4 sub-phases g=0..3 (batch tiles of 16).
// Handoff = round-6 protocol exactly: tagged 8B sc0|sc1 data stores through
// L3, consumers poll the data itself (32x16B sc0|sc1 loads, 2-bit mod-3 tag
// in dword LSBs). By the time a wave returns to tile g at step t+1, peers
// stored tile g ~3 phases earlier -> poll succeeds immediately; the L3
// round-trip latency is hidden behind the other 3 tiles' compute.
__global__ __launch_bounds__(64, 1) void rnn_persist(
    const _Float16* __restrict__ Whf,   // frag-ordered Wh^T
    _Float16* __restrict__ hb0,         // [64][1024] f16 (tagged)
    _Float16* __restrict__ hb1,         // [64][1024] f16 (tagged)
    float* __restrict__ out)            // [64][512][1024]; xp -> h in place
{
    const int cg   = blockIdx.x;        // 0..63 channel group
    const int lane = threadIdx.x;       // 0..63 (one wave per block)
    const int l15  = lane & 15;
    const int lq   = lane >> 4;
    const int c    = cg * 16 + 4 * lq;  // first of this lane's 4 channels

    // Resident A-frags (Wh^T): 32 x f16x8, pinned (live across whole scan).
    f16x8 afrag[32];
    {
        const f16x8* wp = (const f16x8*)Whf + (size_t)cg * 32 * 64 + lane;
#pragma unroll
        for (int kk = 0; kk < 32; ++kk) afrag[kk] = wp[(size_t)kk * 64];
    }
#pragma unroll
    for (int kk = 0; kk < 32; ++kk) asm volatile("" : "+v"(afrag[kk]));

    _Float16* hbuf[2] = {hb0, hb1};

    // Per-phase bases: batch b(g) = g*16 + l15.
    size_t rowoff[4];  // h-row offset of b(g)
    size_t obase[4];   // out offset of (b(g), channel c)
#pragma unroll
    for (int g = 0; g < 4; ++g) {
        int b = g * 16 + l15;
        rowoff[g] = (size_t)b * HH;
        obase[g]  = (size_t)b * TT * HH + c;
    }

    // xp for t=0, all 4 phases.
    f32x4 xpv[4];
#pragma unroll
    for (int g = 0; g < 4; ++g) xpv[g] = *(const f32x4*)(out + obase[g]);

    unsigned tagw = 1u;                 // tag for step t   (1 + t%3)
    unsigned tagr = 0u;                 // tag for step t-1

#pragma unroll 1
    for (int t = 0; t < TT; ++t) {
#pragma unroll
        for (int g = 0; g < 4; ++g) {
            f32x4 acc0 = {0,0,0,0}, acc1 = {0,0,0,0}, acc2 = {0,0,0,0}, acc3 = {0,0,0,0};

            if (t > 0) {
                const _Float16* hp = hbuf[(t + 1) & 1] + rowoff[g] + lq * 8;
                f16x8 bfr[32];
                while (true) {
                    H8U2 uu[32];
#pragma unroll
                    for (int kk = 0; kk < 32; ++kk) {
                        const _Float16* p = hp + kk * 32;
                        asm volatile("global_load_dwordx4 %0, %1, off sc0 sc1"
                                     : "=v"(uu[kk].v) : "v"(p));
                    }
                    __builtin_amdgcn_sched_barrier(0);
                    asm volatile("s_waitcnt vmcnt(0)" ::: "memory");
                    __builtin_amdgcn_sched_barrier(0);

                    unsigned good = 1u;
#pragma unroll
                    for (int kk = 0; kk < 32; ++kk) {
                        u64 lo = uu[kk].u[0], hi = uu[kk].u[1];
                        unsigned ta = (unsigned)(lo & 1u) | (((unsigned)(lo >> 32) & 1u) << 1);
                        unsigned tb = (unsigned)(hi & 1u) | (((unsigned)(hi >> 32) & 1u) << 1);
                        good &= (unsigned)(ta == tagr) & (unsigned)(tb == tagr);
                        bfr[kk] = uu[kk].v;
                    }
                    if (__all((int)good)) break;
                    __builtin_amdgcn_s_sleep(1);
                }
#pragma unroll
                for (int q = 0; q < 8; ++q) {
                    acc0 = MFMA16(afrag[q*4+0], bfr[q*4+0], acc0);
                    acc1 = MFMA16(afrag[q*4+1], bfr[q*4+1], acc1);
                    acc2 = MFMA16(afrag[q*4+2], bfr[q*4+2], acc2);
                    acc3 = MFMA16(afrag[q*4+3], bfr[q*4+3], acc3);
                }
            }

            // h = tanh(acc + xp): 4 consecutive channels of batch b(g).
            f32x4 hvv;
            H4U1 pk;
#pragma unroll
            for (int v = 0; v < 4; ++v) {
                float s = ((acc0[v] + acc1[v]) + (acc2[v] + acc3[v])) + xpv[g][v];
                hvv[v] = tanhf(s);
                pk.h[v] = (_Float16)hvv[v];
            }
            // Embed 2-bit tag: LSB of dword0 = tagw&1, dword1 = tagw>>1.
            pk.u = (pk.u & ~(1ull | (1ull << 32)))
                 | (u64)(tagw & 1u) | ((u64)(tagw >> 1) << 32);

            // One 8B write-through store — the entire inter-wave handoff.
            {
                _Float16* q = hbuf[t & 1] + rowoff[g] + c;
                asm volatile("global_store_dwordx2 %0, %1, off sc0 sc1"
                             :: "v"(q), "v"(pk.u) : "memory");
            }

            // Off critical path: fp32 out store + next xp prefetch.
            *(f32x4*)(out + obase[g] + (size_t)t * HH) = hvv;
            if (t + 1 < TT) xpv[g] = *(const f32x4*)(out + obase[g] + (size_t)(t + 1) * HH);
        }

        tagr = tagw;
        tagw = (tagw == 3u) ? 1u : tagw + 1u;
    }
}

extern "C" void kernel_launch(void* const* d_in, const int* in_sizes, int n_in,
                              void* d_out, int out_size, void* d_ws, size_t ws_size,
                              hipStream_t stream) {
    const float* x    = (const float*)d_in[0]; // [B, T, D]
    const float* Wx   = (const float*)d_in[1]; // [D, H]
    const float* Wh   = (const float*)d_in[2]; // [H, H]
    const float* bias = (const float*)d_in[3]; // [H]

    float* out = (float*)d_out;                // [B, T, H]

    // Workspace: Whf (2MB) | WxA (2MB) | hb0 (128KB) | hb1 (128KB)
    _Float16* Whf = (_Float16*)d_ws;
    _Float16* WxA = Whf + (1u << 20);
    _Float16* hb0 = WxA + (1u << 20);
    _Float16* hb1 = hb0 + BATCH * HH;

    // Weight conversions; the Wh pass also zeroes hb0/hb1 (tag reset, so a
    // graph replay can never see a stale-but-valid tag from a previous run).
    convert_w<<<4096, 256, 0, stream>>>(Wh, Whf, (u64*)hb0);
    convert_w<<<4096, 256, 0, stream>>>(Wx, WxA, nullptr);

    // xp = x @ Wx + bias (f16 MFMA)
    gemm_xp_mfma<<<512, 256, 0, stream>>>(x, WxA, bias, out);

    // Persistent scan: 64 blocks x 64 threads (one wave each), co-resident.
    rnn_persist<<<64, 64, 0, stream>>>(Whf, hb0, hb1, out);
}

// Round 9
// 2312.570 us; speedup vs baseline: 2.5231x; 2.5231x over previous
//
#include <hip/hip_runtime.h>
#include <hip/hip_bf16.h>
#include <hip/hip_fp16.h>
#include <cstddef>

// Problem constants: B=64, T=512, D=1024, H=1024
#define BATCH 64
#define TT    512
#define DD    1024
#define HH    1024

typedef _Float16 f16x8 __attribute__((ext_vector_type(8)));
typedef _Float16 f16x4 __attribute__((ext_vector_type(4)));
typedef float    f32x4 __attribute__((ext_vector_type(4)));
typedef unsigned long long u64;

union H8U2 { f16x8 v; u64 u[2]; };
union H4U1 { f16x4 h; u64 u; };

#define MFMA16(a, b, c) __builtin_amdgcn_mfma_f32_16x16x32_f16((a), (b), (c), 0, 0, 0)

// ---- convert: W [1024][1024] f32 row-major -> A-fragment-order f16 --------
// Wf[((cg*32+kk)*64+lane)*8+e] = W[k][c]  with  k = kk*32+(lane>>4)*8+e,
// c = cg*16+(lane&15).  (Layout verified rounds 1-8.)
// Optionally zeroes the h double-buffer (tag reset; 128 blks x 256 thr x 8B).
__global__ __launch_bounds__(256) void convert_w(
    const float* __restrict__ W, _Float16* __restrict__ Wf,
    u64* __restrict__ hzero)
{
    if (hzero && blockIdx.x < 128)
        hzero[(size_t)blockIdx.x * 256 + threadIdx.x] = 0ull;

    int tid = blockIdx.x * 256 + threadIdx.x;   // tid = k*1024 + c
    int k   = tid >> 10;
    int c   = tid & 1023;
    float v = W[tid];
    int cg   = c >> 4;
    int kk   = k >> 5;
    int lane = ((k >> 3) & 3) * 16 + (c & 15);
    int e    = k & 7;
    Wf[((size_t)(cg * 32 + kk) * 64 + lane) * 8 + e] = (_Float16)v;
}

// ---- Kernel A: xp = x @ Wx + bias via f16 MFMA (unchanged, works) ---------
__global__ __launch_bounds__(256, 1) void gemm_xp_mfma(
    const float* __restrict__ x,     // [32768][1024] f32
    const _Float16* __restrict__ WxA,// frag-ordered Wx^T
    const float* __restrict__ bias,  // [1024]
    float* __restrict__ out)         // [32768][1024] -> xp
{
    const int w    = threadIdx.x >> 6;
    const int lane = threadIdx.x & 63;
    const int l15  = lane & 15;
    const int lq   = lane >> 4;
    const int token0 = (blockIdx.x * 4 + w) * 16;

    f16x8 bfrag[32];
    {
        const float* xb = x + (size_t)(token0 + l15) * DD + lq * 8;
#pragma unroll
        for (int kk = 0; kk < 32; ++kk) {
            f32x4 lo = *(const f32x4*)(xb + kk * 32);
            f32x4 hi = *(const f32x4*)(xb + kk * 32 + 4);
            f16x8 f;
#pragma unroll
            for (int j = 0; j < 4; ++j) { f[j] = (_Float16)lo[j]; f[4 + j] = (_Float16)hi[j]; }
            bfrag[kk] = f;
        }
    }
#pragma unroll
    for (int kk = 0; kk < 32; ++kk) asm volatile("" : "+v"(bfrag[kk]));

    const size_t outb = (size_t)(token0 + l15) * HH + 4 * lq;

    for (int cg = 0; cg < 64; ++cg) {
        const f16x8* ap = (const f16x8*)WxA + (size_t)cg * 32 * 64 + lane;
        f16x8 a[32];
#pragma unroll
        for (int kk = 0; kk < 32; ++kk) a[kk] = ap[(size_t)kk * 64];

        f32x4 acc0 = {0,0,0,0}, acc1 = {0,0,0,0}, acc2 = {0,0,0,0}, acc3 = {0,0,0,0};
#pragma unroll
        for (int q = 0; q < 8; ++q) {
            acc0 = MFMA16(a[q*4+0], bfrag[q*4+0], acc0);
            acc1 = MFMA16(a[q*4+1], bfrag[q*4+1], acc1);
            acc2 = MFMA16(a[q*4+2], bfrag[q*4+2], acc2);
            acc3 = MFMA16(a[q*4+3], bfrag[q*4+3], acc3);
        }
        f32x4 bv = *(const f32x4*)(bias + cg * 16 + 4 * lq);
        f32x4 r;
#pragma unroll
        for (int v = 0; v < 4; ++v)
            r[v] = ((acc0[v] + acc1[v]) + (acc2[v] + acc3[v])) + bv[v];
        *(f32x4*)(out + outb + cg * 16) = r;
    }
}

// ---- Kernel B: persistent scan with LDS-deduped h broadcast ---------------
// 32 blocks x 512 threads (8 waves). Block = (bg = bid&3, co = bid>>2);
// wave w owns cg = co*8 + w. Per step: block stages h[bg rows] (32 KB) into
// LDS ONCE (512 threads poll-load 4x16B tagged granules each, R6 protocol),
// __syncthreads, then all 8 waves ds_read B-frags from LDS (XOR-swizzled)
// and MFMA against pinned Wh^T A-frags. Cuts the h L3 broadcast 8x.
// Producer side unchanged: tagged 8B sc0|sc1 stores, mod-3 tags, 2 buffers.
__global__ __launch_bounds__(512, 2) void rnn_persist(
    const _Float16* __restrict__ Whf,   // frag-ordered Wh^T
    _Float16* __restrict__ hb0,         // [64][1024] f16 (tagged)
    _Float16* __restrict__ hb1,         // [64][1024] f16 (tagged)
    float* __restrict__ out)            // [64][512][1024]; xp -> h in place
{
    __shared__ char ldsraw[65536];      // 2 x 32 KB h-tile double buffer

    const int tid  = threadIdx.x;
    const int bg   = blockIdx.x & 3;        // batch group (16 rows)
    const int co   = blockIdx.x >> 2;       // channel octet
    const int w    = tid >> 6;
    const int cg   = co * 8 + w;            // 0..63 channel group
    const int lane = tid & 63;
    const int l15  = lane & 15;
    const int lq   = lane >> 4;

    // Resident A-frags (Wh^T): 32 x f16x8, pinned (live across whole scan).
    f16x8 afrag[32];
    {
        const f16x8* wp = (const f16x8*)Whf + (size_t)cg * 32 * 64 + lane;
#pragma unroll
        for (int kk = 0; kk < 32; ++kk) afrag[kk] = wp[(size_t)kk * 64];
    }
#pragma unroll
    for (int kk = 0; kk < 32; ++kk) asm volatile("" : "+v"(afrag[kk]));

    _Float16* hbuf[2] = {hb0, hb1};

    const int b = bg * 16 + l15;            // this lane's batch row (epilogue)
    const int c = cg * 16 + 4 * lq;         // first of this lane's 4 channels
    const size_t ob = (size_t)b * TT * HH + c;

    // Stage-phase constants: thread handles granules gi = tid + 512*i.
    int srow[4], scolg[4]; unsigned soff[4];
#pragma unroll
    for (int i = 0; i < 4; ++i) {
        int gi  = tid + 512 * i;
        srow[i]  = gi >> 7;
        scolg[i] = gi & 127;
        soff[i]  = (unsigned)gi * 16u;      // linear byte offset in 32 KB tile
    }

    f32x4 xpv = *(const f32x4*)(out + ob);  // xp for t=0

    for (int t = 0; t < TT; ++t) {
        // ---- stage h_{t-1}[bg] into LDS (tag-poll, then ds_write) ----
        if (t > 0) {
            const unsigned tagr = 1u + (unsigned)((t - 1) % 3);
            const _Float16* hp = hbuf[(t + 1) & 1];
            H8U2 uu[4];
            const _Float16* src[4];
#pragma unroll
            for (int i = 0; i < 4; ++i)
                src[i] = hp + (size_t)(bg * 16 + srow[i]) * HH + scolg[i] * 8;

            while (true) {
#pragma unroll
                for (int i = 0; i < 4; ++i)
                    asm volatile("global_load_dwordx4 %0, %1, off sc0 sc1"
                                 : "=v"(uu[i].v) : "v"(src[i]));
                __builtin_amdgcn_sched_barrier(0);
                asm volatile("s_waitcnt vmcnt(0)" ::: "memory");
                __builtin_amdgcn_sched_barrier(0);

                unsigned good = 1u;
#pragma unroll
                for (int i = 0; i < 4; ++i) {
                    u64 lo = uu[i].u[0], hi = uu[i].u[1];
                    unsigned ta = (unsigned)(lo & 1u) | (((unsigned)(lo >> 32) & 1u) << 1);
                    unsigned tb = (unsigned)(hi & 1u) | (((unsigned)(hi >> 32) & 1u) << 1);
                    good &= (unsigned)(ta == tagr) & (unsigned)(tb == tagr);
                }
                if (good) break;
                __builtin_amdgcn_s_sleep(1);
            }

            char* lb = ldsraw + (t & 1) * 32768;
#pragma unroll
            for (int i = 0; i < 4; ++i) {
                unsigned o = soff[i] ^ (unsigned)((srow[i] & 7) << 4);  // bank swizzle
                *(f16x8*)(lb + o) = uu[i].v;
            }
        }
        __syncthreads();

        // ---- compute: B-frags from LDS, MFMA vs pinned afrag ----
        f32x4 acc0 = {0,0,0,0}, acc1 = {0,0,0,0}, acc2 = {0,0,0,0}, acc3 = {0,0,0,0};
        if (t > 0) {
            const char* lb = ldsraw + (t & 1) * 32768;
            const unsigned rbase = (unsigned)(l15 * 2048);
            const unsigned rswz  = (unsigned)((l15 & 7) << 4);
#pragma unroll
            for (int q = 0; q < 8; ++q) {
                f16x8 b0, b1, b2, b3;
                b0 = *(const f16x8*)(lb + ((rbase + ((q*16 + 0*4 + lq) * 16u)) ^ rswz));
                b1 = *(const f16x8*)(lb + ((rbase + ((q*16 + 1*4 + lq) * 16u)) ^ rswz));
                b2 = *(const f16x8*)(lb + ((rbase + ((q*16 + 2*4 + lq) * 16u)) ^ rswz));
                b3 = *(const f16x8*)(lb + ((rbase + ((q*16 + 3*4 + lq) * 16u)) ^ rswz));
                acc0 = MFMA16(afrag[q*4+0], b0, acc0);
                acc1 = MFMA16(afrag[q*4+1], b1, acc1);
                acc2 = MFMA16(afrag[q*4+2], b2, acc2);
                acc3 = MFMA16(afrag[q*4+3], b3, acc3);
            }
        }

        // ---- epilogue: h = tanh(acc + xp), tagged h-store, out, prefetch --
        const unsigned tagw = 1u + (unsigned)(t % 3);
        f32x4 hvv;
        H4U1 pk;
#pragma unroll
        for (int v = 0; v < 4; ++v) {
            float s = ((acc0[v] + acc1[v]) + (acc2[v] + acc3[v])) + xpv[v];
            hvv[v] = tanhf(s);
            pk.h[v] = (_Float16)hvv[v];
        }
        pk.u = (pk.u & ~(1ull | (1ull << 32)))
             | (u64)(tagw & 1u) | ((u64)(tagw >> 1) << 32);

        {
            _Float16* q = hbuf[t & 1] + (size_t)b * HH + c;
            asm volatile("global_store_dwordx2 %0, %1, off sc0 sc1"
                         :: "v"(q), "v"(pk.u) : "memory");
        }

        *(f32x4*)(out + ob + (size_t)t * HH) = hvv;
        if (t + 1 < TT) xpv = *(const f32x4*)(out + ob + (size_t)(t + 1) * HH);
    }
}

extern "C" void kernel_launch(void* const* d_in, const int* in_sizes, int n_in,
                              void* d_out, int out_size, void* d_ws, size_t ws_size,
                              hipStream_t stream) {
    const float* x    = (const float*)d_in[0]; // [B, T, D]
    const float* Wx   = (const float*)d_in[1]; // [D, H]
    const float* Wh   = (const float*)d_in[2]; // [H, H]
    const float* bias = (const float*)d_in[3]; // [H]

    float* out = (float*)d_out;                // [B, T, H]

    // Workspace: Whf (2MB) | WxA (2MB) | hb0 (128KB) | hb1 (128KB)
    _Float16* Whf = (_Float16*)d_ws;
    _Float16* WxA = Whf + (1u << 20);
    _Float16* hb0 = WxA + (1u << 20);
    _Float16* hb1 = hb0 + BATCH * HH;

    // Weight conversions; the Wh pass also zeroes hb0/hb1 (tag reset, so a
    // graph replay can never see a stale-but-valid tag from a previous run).
    convert_w<<<4096, 256, 0, stream>>>(Wh, Whf, (u64*)hb0);
    convert_w<<<4096, 256, 0, stream>>>(Wx, WxA, nullptr);

    // xp = x @ Wx + bias (f16 MFMA)
    gemm_xp_mfma<<<512, 256, 0, stream>>>(x, WxA, bias, out);

    // Persistent scan: 32 blocks x 512 threads (8 waves), co-resident.
    rnn_persist<<<32, 512, 0, stream>>>(Whf, hb0, hb1, out);
}

// Round 10
// 2256.082 us; speedup vs baseline: 2.5863x; 1.0250x over previous
//
#include <hip/hip_runtime.h>
#include <hip/hip_bf16.h>
#include <hip/hip_fp16.h>
#include <cstddef>

// Problem constants: B=64, T=512, D=1024, H=1024
#define BATCH 64
#define TT    512
#define DD    1024
#define HH    1024

typedef _Float16 f16x8 __attribute__((ext_vector_type(8)));
typedef _Float16 f16x4 __attribute__((ext_vector_type(4)));
typedef float    f32x4 __attribute__((ext_vector_type(4)));
typedef unsigned long long u64;

union H8U2 { f16x8 v; u64 u[2]; };
union H4U1 { f16x4 h; u64 u; };

#define MFMA16(a, b, c) __builtin_amdgcn_mfma_f32_16x16x32_f16((a), (b), (c), 0, 0, 0)

// ---- convert: W [1024][1024] f32 row-major -> A-fragment-order f16 --------
// Wf[((cg*32+kk)*64+lane)*8+e] = W[k][c]  with  k = kk*32+(lane>>4)*8+e,
// c = cg*16+(lane&15).  (Layout verified rounds 1-9.)
// Optionally zeroes the h double-buffer (tag reset; 128 blks x 256 thr x 8B).
__global__ __launch_bounds__(256) void convert_w(
    const float* __restrict__ W, _Float16* __restrict__ Wf,
    u64* __restrict__ hzero)
{
    if (hzero && blockIdx.x < 128)
        hzero[(size_t)blockIdx.x * 256 + threadIdx.x] = 0ull;

    int tid = blockIdx.x * 256 + threadIdx.x;   // tid = k*1024 + c
    int k   = tid >> 10;
    int c   = tid & 1023;
    float v = W[tid];
    int cg   = c >> 4;
    int kk   = k >> 5;
    int lane = ((k >> 3) & 3) * 16 + (c & 15);
    int e    = k & 7;
    Wf[((size_t)(cg * 32 + kk) * 64 + lane) * 8 + e] = (_Float16)v;
}

// ---- Kernel A: xp = x @ Wx + bias via f16 MFMA (unchanged, works) ---------
__global__ __launch_bounds__(256, 1) void gemm_xp_mfma(
    const float* __restrict__ x,     // [32768][1024] f32
    const _Float16* __restrict__ WxA,// frag-ordered Wx^T
    const float* __restrict__ bias,  // [1024]
    float* __restrict__ out)         // [32768][1024] -> xp
{
    const int w    = threadIdx.x >> 6;
    const int lane = threadIdx.x & 63;
    const int l15  = lane & 15;
    const int lq   = lane >> 4;
    const int token0 = (blockIdx.x * 4 + w) * 16;

    f16x8 bfrag[32];
    {
        const float* xb = x + (size_t)(token0 + l15) * DD + lq * 8;
#pragma unroll
        for (int kk = 0; kk < 32; ++kk) {
            f32x4 lo = *(const f32x4*)(xb + kk * 32);
            f32x4 hi = *(const f32x4*)(xb + kk * 32 + 4);
            f16x8 f;
#pragma unroll
            for (int j = 0; j < 4; ++j) { f[j] = (_Float16)lo[j]; f[4 + j] = (_Float16)hi[j]; }
            bfrag[kk] = f;
        }
    }
#pragma unroll
    for (int kk = 0; kk < 32; ++kk) asm volatile("" : "+v"(bfrag[kk]));

    const size_t outb = (size_t)(token0 + l15) * HH + 4 * lq;

    for (int cg = 0; cg < 64; ++cg) {
        const f16x8* ap = (const f16x8*)WxA + (size_t)cg * 32 * 64 + lane;
        f16x8 a[32];
#pragma unroll
        for (int kk = 0; kk < 32; ++kk) a[kk] = ap[(size_t)kk * 64];

        f32x4 acc0 = {0,0,0,0}, acc1 = {0,0,0,0}, acc2 = {0,0,0,0}, acc3 = {0,0,0,0};
#pragma unroll
        for (int q = 0; q < 8; ++q) {
            acc0 = MFMA16(a[q*4+0], bfrag[q*4+0], acc0);
            acc1 = MFMA16(a[q*4+1], bfrag[q*4+1], acc1);
            acc2 = MFMA16(a[q*4+2], bfrag[q*4+2], acc2);
            acc3 = MFMA16(a[q*4+3], bfrag[q*4+3], acc3);
        }
        f32x4 bv = *(const f32x4*)(bias + cg * 16 + 4 * lq);
        f32x4 r;
#pragma unroll
        for (int v = 0; v < 4; ++v)
            r[v] = ((acc0[v] + acc1[v]) + (acc2[v] + acc3[v])) + bv[v];
        *(f32x4*)(out + outb + cg * 16) = r;
    }
}

// ---- Kernel B: persistent scan, LDS-deduped broadcast, early-issued polls -
// 64 blocks x 256 threads (4 waves). Block = (bg = bid&3, co4 = bid>>2);
// wave w owns cg = co4*4 + w. Per step: block stages h[bg rows] (32 KB) into
// LDS once (256 threads x 8 tagged 16B granules, R6 tag protocol), syncs,
// then 4 waves ds_read B-frags (XOR-swizzled) + MFMA vs pinned Wh^T frags.
// The stage loads for step t+1 are ISSUED right after the step-t h-store, so
// the L3 round-trip overlaps the epilogue instead of the critical path.
__global__ __launch_bounds__(256, 1) void rnn_persist(
    const _Float16* __restrict__ Whf,   // frag-ordered Wh^T
    _Float16* __restrict__ hb0,         // [64][1024] f16 (tagged)
    _Float16* __restrict__ hb1,         // [64][1024] f16 (tagged)
    float* __restrict__ out)            // [64][512][1024]; xp -> h in place
{
    __shared__ char ldsraw[65536];      // 2 x 32 KB h-tile double buffer

    const int tid  = threadIdx.x;
    const int bg   = blockIdx.x & 3;        // batch group (16 rows)
    const int co4  = blockIdx.x >> 2;       // channel quad (4 cgs)
    const int w    = tid >> 6;
    const int cg   = co4 * 4 + w;           // 0..63 channel group
    const int lane = tid & 63;
    const int l15  = lane & 15;
    const int lq   = lane >> 4;

    // Resident A-frags (Wh^T): 32 x f16x8, pinned (live across whole scan).
    f16x8 afrag[32];
    {
        const f16x8* wp = (const f16x8*)Whf + (size_t)cg * 32 * 64 + lane;
#pragma unroll
        for (int kk = 0; kk < 32; ++kk) afrag[kk] = wp[(size_t)kk * 64];
    }
#pragma unroll
    for (int kk = 0; kk < 32; ++kk) asm volatile("" : "+v"(afrag[kk]));

    _Float16* hbuf[2] = {hb0, hb1};

    const int b = bg * 16 + l15;            // this lane's batch row (epilogue)
    const int c = cg * 16 + 4 * lq;         // first of this lane's 4 channels
    const size_t ob = (size_t)b * TT * HH + c;

    // Stage-phase constants: thread handles granules gi = tid + 256*i, i<8.
    unsigned soff[8];                       // swizzled LDS byte offsets
    const _Float16* src0[8];                // source in hb0
    const _Float16* src1[8];                // source in hb1
#pragma unroll
    for (int i = 0; i < 8; ++i) {
        int gi   = tid + 256 * i;
        int srow = gi >> 7;                 // 0..15 within the bg tile
        int scol = gi & 127;                // 16B granule within row
        soff[i]  = ((unsigned)gi * 16u) ^ (unsigned)((srow & 7) << 4);
        src0[i]  = hb0 + (size_t)(bg * 16 + srow) * HH + scol * 8;
        src1[i]  = hb1 + (size_t)(bg * 16 + srow) * HH + scol * 8;
    }

    f32x4 xpv = *(const f32x4*)(out + ob);  // xp for t=0

    H8U2 uu[8];                             // in-flight stage loads

    for (int t = 0; t < TT; ++t) {
        // ---- complete/verify staged h_{t-1}, write to LDS ----
        if (t > 0) {
            const unsigned tagr = 1u + (unsigned)((t - 1) % 3);
            const _Float16* const* src = ((t + 1) & 1) ? src1 : src0;
            // Loads were issued at the end of step t-1; finish and check.
            while (true) {
                __builtin_amdgcn_sched_barrier(0);
                asm volatile("s_waitcnt vmcnt(0)" ::: "memory");
                __builtin_amdgcn_sched_barrier(0);

                unsigned good = 1u;
#pragma unroll
                for (int i = 0; i < 8; ++i) {
                    u64 lo = uu[i].u[0], hi = uu[i].u[1];
                    unsigned ta = (unsigned)(lo & 1u) | (((unsigned)(lo >> 32) & 1u) << 1);
                    unsigned tb = (unsigned)(hi & 1u) | (((unsigned)(hi >> 32) & 1u) << 1);
                    good &= (unsigned)(ta == tagr) & (unsigned)(tb == tagr);
                }
                if (good) break;
                __builtin_amdgcn_s_sleep(1);
#pragma unroll
                for (int i = 0; i < 8; ++i)
                    asm volatile("global_load_dwordx4 %0, %1, off sc0 sc1"
                                 : "=v"(uu[i].v) : "v"(src[i]));
            }

            char* lb = ldsraw + (t & 1) * 32768;
#pragma unroll
            for (int i = 0; i < 8; ++i)
                *(f16x8*)(lb + soff[i]) = uu[i].v;
        }
        __syncthreads();

        // ---- compute: B-frags from LDS, MFMA vs pinned afrag ----
        f32x4 acc0 = {0,0,0,0}, acc1 = {0,0,0,0}, acc2 = {0,0,0,0}, acc3 = {0,0,0,0};
        if (t > 0) {
            const char* lb = ldsraw + (t & 1) * 32768;
            const unsigned rbase = (unsigned)(l15 * 2048);
            const unsigned rswz  = (unsigned)((l15 & 7) << 4);
#pragma unroll
            for (int q = 0; q < 8; ++q) {
                f16x8 b0, b1, b2, b3;
                b0 = *(const f16x8*)(lb + ((rbase + ((q*16 + 0*4 + lq) * 16u)) ^ rswz));
                b1 = *(const f16x8*)(lb + ((rbase + ((q*16 + 1*4 + lq) * 16u)) ^ rswz));
                b2 = *(const f16x8*)(lb + ((rbase + ((q*16 + 2*4 + lq) * 16u)) ^ rswz));
                b3 = *(const f16x8*)(lb + ((rbase + ((q*16 + 3*4 + lq) * 16u)) ^ rswz));
                acc0 = MFMA16(afrag[q*4+0], b0, acc0);
                acc1 = MFMA16(afrag[q*4+1], b1, acc1);
                acc2 = MFMA16(afrag[q*4+2], b2, acc2);
                acc3 = MFMA16(afrag[q*4+3], b3, acc3);
            }
        }

        // ---- epilogue: h = tanh(acc + xp), tagged h-store ----
        const unsigned tagw = 1u + (unsigned)(t % 3);
        f32x4 hvv;
        H4U1 pk;
#pragma unroll
        for (int v = 0; v < 4; ++v) {
            float s = ((acc0[v] + acc1[v]) + (acc2[v] + acc3[v])) + xpv[v];
            hvv[v] = tanhf(s);
            pk.h[v] = (_Float16)hvv[v];
        }
        pk.u = (pk.u & ~(1ull | (1ull << 32)))
             | (u64)(tagw & 1u) | ((u64)(tagw >> 1) << 32);

        {
            _Float16* q = hbuf[t & 1] + (size_t)b * HH + c;
            asm volatile("global_store_dwordx2 %0, %1, off sc0 sc1"
                         :: "v"(q), "v"(pk.u) : "memory");
        }

        // ---- issue next step's stage loads EARLY (overlap L3 RTT) ----
        if (t + 1 < TT) {
            const _Float16* const* src = (t & 1) ? src1 : src0;  // hbuf[t&1]
#pragma unroll
            for (int i = 0; i < 8; ++i)
                asm volatile("global_load_dwordx4 %0, %1, off sc0 sc1"
                             : "=v"(uu[i].v) : "v"(src[i]));
        }

        // ---- off critical path: fp32 out store + next xp prefetch ----
        *(f32x4*)(out + ob + (size_t)t * HH) = hvv;
        if (t + 1 < TT) xpv = *(const f32x4*)(out + ob + (size_t)(t + 1) * HH);
    }
}

extern "C" void kernel_launch(void* const* d_in, const int* in_sizes, int n_in,
                              void* d_out, int out_size, void* d_ws, size_t ws_size,
                              hipStream_t stream) {
    const float* x    = (const float*)d_in[0]; // [B, T, D]
    const float* Wx   = (const float*)d_in[1]; // [D, H]
    const float* Wh   = (const float*)d_in[2]; // [H, H]
    const float* bias = (const float*)d_in[3]; // [H]

    float* out = (float*)d_out;                // [B, T, H]

    // Workspace: Whf (2MB) | WxA (2MB) | hb0 (128KB) | hb1 (128KB)
    _Float16* Whf = (_Float16*)d_ws;
    _Float16* WxA = Whf + (1u << 20);
    _Float16* hb0 = WxA + (1u << 20);
    _Float16* hb1 = hb0 + BATCH * HH;

    // Weight conversions; the Wh pass also zeroes hb0/hb1 (tag reset, so a
    // graph replay can never see a stale-but-valid tag from a previous run).
    convert_w<<<4096, 256, 0, stream>>>(Wh, Whf, (u64*)hb0);
    convert_w<<<4096, 256, 0, stream>>>(Wx, WxA, nullptr);

    // xp = x @ Wx + bias (f16 MFMA)
    gemm_xp_mfma<<<512, 256, 0, stream>>>(x, WxA, bias, out);

    // Persistent scan: 64 blocks x 256 threads (4 waves), co-resident.
    rnn_persist<<<64, 256, 0, stream>>>(Whf, hb0, hb1, out);
}